// Round 7
// baseline (212.825 us; speedup 1.0000x reference)
//
#include <hip/hip_runtime.h>

// LengthRegulator: B=32, T=512, D=384, DUR_MAX=8, L = 512*7 = 3584
// Frame-partitioned fused kernel: each block owns 128 output frames of one
// batch -> writes exactly 192 KiB dense (uniform, fill-like). Per block:
// recompute batch scan (L2-hit dur), scatter token ids for its frame range
// into LDS sidx[128], then stream out[f,w] = x[sidx[f],w] with coalesced
// reads AND writes. Zero tail via sidx = -1. One launch, no d_ws.

#define B_DIM 32
#define T_DIM 512
#define D_DIM 384
#define L_DIM 3584
#define VEC 96                          // f32x4 per frame row
#define F_PB 128                        // frames per block
#define CPB (L_DIM / F_PB)              // 28 chunks per batch
#define BLOCKS (B_DIM * CPB)            // 896
#define F4_PB (F_PB * VEC)              // 12288 f4 per block
#define ITERS (F4_PB / 256)             // 48 per thread

typedef float f32x4 __attribute__((ext_vector_type(4)));

__global__ void __launch_bounds__(256)
lr_fused(const f32x4* __restrict__ x, const int* __restrict__ dur,
         f32x4* __restrict__ out, float* __restrict__ mel_out) {
    const int blk  = blockIdx.x;
    const int b    = blk / CPB;         // const divisor (28)
    const int c    = blk - b * CPB;
    const int f0   = c * F_PB;
    const int t    = threadIdx.x;       // 0..255
    const int lane = t & 63;
    const int wv   = t >> 6;            // 0..3

    // ---- full-batch scan: thread t owns tokens 2t, 2t+1
    const int2 dd = ((const int2*)(dur + b * T_DIM))[t];
    const int e0 = dd.x > 1 ? dd.x : 1;
    const int e1 = dd.y > 1 ? dd.y : 1;

    int val = e0 + e1;                  // wave inclusive scan of pair-sums
    #pragma unroll
    for (int off = 1; off < 64; off <<= 1) {
        int n = __shfl_up(val, off, 64);
        if (lane >= off) val += n;
    }

    __shared__ int wsum[4];
    __shared__ int sidx[F_PB];          // token id per frame in block range
    if (lane == 63) wsum[wv] = val;
    if (t < F_PB) sidx[t] = -1;         // default: zero-frame (tail)
    __syncthreads();

    int base = 0, tot = 0;
    #pragma unroll
    for (int i = 0; i < 4; ++i) {
        int w = wsum[i];
        tot += w;
        if (i < wv) base += w;
    }
    const int cum1 = val + base;        // inclusive cum of token 2t+1
    const int cum0 = cum1 - e1;         // inclusive cum of token 2t
    const int prev = cum0 - e0;         // cum of token 2t-1

    // ---- scatter: write token id into sidx for frames in [f0, f0+F_PB)
    const int f1 = f0 + F_PB;
    {
        int lo = prev > f0 ? prev : f0;
        int hi = cum0 < f1 ? cum0 : f1;
        for (int f = lo; f < hi; ++f) sidx[f - f0] = 2 * t;
        lo = cum0 > f0 ? cum0 : f0;
        hi = cum1 < f1 ? cum1 : f1;
        for (int f = lo; f < hi; ++f) sidx[f - f0] = 2 * t + 1;
    }
    __syncthreads();

    if (c == 0 && t == 0)
        mel_out[b] = (float)tot;

    // ---- uniform dense stream: 48 f4 per thread, coalesced both ways
    const f32x4* xb = x + (size_t)b * T_DIM * VEC;
    f32x4*       ob = out + ((size_t)b * L_DIM + f0) * VEC;

    #pragma unroll 8
    for (int i = 0; i < ITERS; ++i) {
        const int v  = t + i * 256;
        const int fl = v / VEC;         // const divisor (96)
        const int w  = v - fl * VEC;
        const int id = sidx[fl];        // LDS broadcast within frame
        f32x4 r = (f32x4)0.f;
        if (id >= 0)
            r = xb[id * VEC + w];       // L1/L2-served duplicates
        ob[v] = r;
    }
}

extern "C" void kernel_launch(void* const* d_in, const int* in_sizes, int n_in,
                              void* d_out, int out_size, void* d_ws, size_t ws_size,
                              hipStream_t stream) {
    const float* x   = (const float*)d_in[0];
    const int*   dur = (const int*)d_in[1];

    float* out     = (float*)d_out;
    float* mel_out = out + (size_t)B_DIM * L_DIM * D_DIM; // mel_len tail as f32

    lr_fused<<<dim3(BLOCKS), dim3(256), 0, stream>>>(
        (const f32x4*)x, dur, (f32x4*)out, mel_out);
}

// Round 8
// 201.778 us; speedup vs baseline: 1.0547x; 1.0547x over previous
//
#include <hip/hip_runtime.h>

// LengthRegulator: B=32, T=512, D=384, DUR_MAX=8, L = 512*7 = 3584
// Frame-major fused kernel, small chunks: each block owns 32 output frames
// of one batch (48 KiB dense, uniform, fill-like). 3584 blocks = 14/CU
// (refill pool; zero-tail blocks finish early and free CUs). Per block:
// recompute batch scan (L2-hot dur), scatter token ids for its 32-frame
// window into LDS sidx[32], then stream out = x[sidx[f]] with coalesced
// reads and writes. Zero tail via sidx = -1. One launch, no d_ws.

#define B_DIM 32
#define T_DIM 512
#define D_DIM 384
#define L_DIM 3584
#define VEC 96                          // f32x4 per frame row
#define F_PB 32                         // frames per block
#define CPB (L_DIM / F_PB)              // 112 chunks per batch
#define BLOCKS (B_DIM * CPB)            // 3584 = 14 per CU
#define ITERS (F_PB * VEC / 256)        // 12 f4 per thread

typedef float f32x4 __attribute__((ext_vector_type(4)));

__global__ void __launch_bounds__(256)
lr_fused(const f32x4* __restrict__ x, const int* __restrict__ dur,
         f32x4* __restrict__ out, float* __restrict__ mel_out) {
    const int blk  = blockIdx.x;
    const int b    = blk / CPB;         // const divisor (112)
    const int c    = blk - b * CPB;
    const int f0   = c * F_PB;
    const int t    = threadIdx.x;       // 0..255
    const int lane = t & 63;
    const int wv   = t >> 6;            // 0..3

    // ---- full-batch scan: thread t owns tokens 2t, 2t+1
    const int2 dd = ((const int2*)(dur + b * T_DIM))[t];
    const int e0 = dd.x > 1 ? dd.x : 1;
    const int e1 = dd.y > 1 ? dd.y : 1;

    int val = e0 + e1;                  // wave inclusive scan of pair-sums
    #pragma unroll
    for (int off = 1; off < 64; off <<= 1) {
        int n = __shfl_up(val, off, 64);
        if (lane >= off) val += n;
    }

    __shared__ int wsum[4];
    __shared__ int sidx[F_PB];          // token id per frame in window
    if (lane == 63) wsum[wv] = val;
    if (t < F_PB) sidx[t] = -1;         // default: zero frame (tail)
    __syncthreads();

    int base = 0, tot = 0;
    #pragma unroll
    for (int i = 0; i < 4; ++i) {
        int w = wsum[i];
        tot += w;
        if (i < wv) base += w;
    }
    const int cum1 = val + base;        // inclusive cum of token 2t+1
    const int cum0 = cum1 - e1;         // inclusive cum of token 2t
    const int prev = cum0 - e0;         // cum of token 2t-1

    // ---- scatter token ids covering [f0, f0+F_PB)
    const int f1 = f0 + F_PB;
    {
        int lo = prev > f0 ? prev : f0;
        int hi = cum0 < f1 ? cum0 : f1;
        for (int f = lo; f < hi; ++f) sidx[f - f0] = 2 * t;
        lo = cum0 > f0 ? cum0 : f0;
        hi = cum1 < f1 ? cum1 : f1;
        for (int f = lo; f < hi; ++f) sidx[f - f0] = 2 * t + 1;
    }
    __syncthreads();

    if (c == 0 && t == 0)
        mel_out[b] = (float)tot;

    // ---- uniform dense stream: 12 f4 per thread, coalesced both ways
    const f32x4* xb = x + (size_t)b * T_DIM * VEC;
    f32x4*       ob = out + ((size_t)b * L_DIM + f0) * VEC;

    #pragma unroll
    for (int i = 0; i < ITERS; ++i) {
        const int v  = t + i * 256;
        const int fl = v / VEC;         // const divisor (96)
        const int w  = v - fl * VEC;
        const int id = sidx[fl];        // LDS broadcast within frame
        f32x4 r = (f32x4)0.f;
        if (id >= 0)
            r = xb[id * VEC + w];       // L1/L2-served (x is L3-warm)
        ob[v] = r;
    }
}

extern "C" void kernel_launch(void* const* d_in, const int* in_sizes, int n_in,
                              void* d_out, int out_size, void* d_ws, size_t ws_size,
                              hipStream_t stream) {
    const float* x   = (const float*)d_in[0];
    const int*   dur = (const int*)d_in[1];

    float* out     = (float*)d_out;
    float* mel_out = out + (size_t)B_DIM * L_DIM * D_DIM; // mel_len tail as f32

    lr_fused<<<dim3(BLOCKS), dim3(256), 0, stream>>>(
        (const f32x4*)x, dur, (f32x4*)out, mel_out);
}